// Round 1
// baseline (4190.562 us; speedup 1.0000x reference)
//
#include <hip/hip_runtime.h>

// ---------------------------------------------------------------------------
// Social LSTM model, fp32 baseline.
//   enc:  LSTM(2->64), T=50, agent (2048 seqs) + neighbours (32768 seqs)
//   pool: masked max over valid neighbours, concat -> h0 [2048,128]
//   dec:  LSTMCell(128->128) fed its own h, 30 steps, pred = h@Wpos.T + bpos
// Strategy: one wave owns a group of sequences; h stays in registers and is
// broadcast with v_readlane (no barriers in the recurrence). Whh packed
// transposed as float4{i,f,g,o} per (k, unit) in LDS (64 KiB, conflict-free
// b128 reads). Decoder streams fused (Wih+Whh) weights from L2.
// ---------------------------------------------------------------------------

#define H_ENC 64
#define H_DEC 128
#define T_SEQ 50
#define PRED_STEPS 30
#define B_SZ 2048
#define NMAX 16

// ws layout (float offsets)
static constexpr size_t OFF_AEMB = 0;                       // 2048*64
static constexpr size_t OFF_NENC = 131072;                  // 32768*64
static constexpr size_t OFF_H0   = 2228224;                 // 2048*128
static constexpr size_t OFF_WA   = 2490368;                 // 17152 (4096 f4 W + 64 f4 wi0 + 64 f4 wi1 + 64 f4 b)
static constexpr size_t OFF_WN   = 2507520;                 // 17152
static constexpr size_t OFF_WD   = 2524672;                 // 65536 + 512

__device__ __forceinline__ float rlf(float v, int l) {
  return __uint_as_float((unsigned)__builtin_amdgcn_readlane((int)__float_as_uint(v), l));
}
__device__ __forceinline__ float frcp(float x) { return __builtin_amdgcn_rcpf(x); }
__device__ __forceinline__ float sigf(float x) { return frcp(1.f + __expf(-x)); }
__device__ __forceinline__ float tanhf_fast(float x) {
  float ax = fabsf(x);
  float t = __expf(-2.f * ax);
  float r = 1.f - 2.f * t * frcp(1.f + t);
  return copysignf(r, x);
}
__device__ __forceinline__ float4 axpy(float4 a, float4 w, float s) {
  a.x = fmaf(w.x, s, a.x); a.y = fmaf(w.y, s, a.y);
  a.z = fmaf(w.z, s, a.z); a.w = fmaf(w.w, s, a.w);
  return a;
}

// ---------------------------------------------------------------------------
// Prep: pack encoder weights.  pack[k*64+j] = {Whh[g*64+j][k]}_{g=0..3},
// then wi0/wi1 (input cols) and fused bias, one float4 per unit j.
// ---------------------------------------------------------------------------
__global__ void prep_enc_kernel(const float* __restrict__ Wih_a, const float* __restrict__ Whh_a,
                                const float* __restrict__ bih_a, const float* __restrict__ bhh_a,
                                const float* __restrict__ Wih_n, const float* __restrict__ Whh_n,
                                const float* __restrict__ bih_n, const float* __restrict__ bhh_n,
                                float* __restrict__ wsf) {
  const int which = blockIdx.x;
  const float* Wih = which ? Wih_n : Wih_a;
  const float* Whh = which ? Whh_n : Whh_a;
  const float* bih = which ? bih_n : bih_a;
  const float* bhh = which ? bhh_n : bhh_a;
  float4* pack = (float4*)(wsf + (which ? OFF_WN : OFF_WA));
  for (int idx = threadIdx.x; idx < 4096; idx += 256) {
    int k = idx >> 6, j = idx & 63;
    float4 v;
    v.x = Whh[(0 * 64 + j) * 64 + k];
    v.y = Whh[(1 * 64 + j) * 64 + k];
    v.z = Whh[(2 * 64 + j) * 64 + k];
    v.w = Whh[(3 * 64 + j) * 64 + k];
    pack[idx] = v;
  }
  if (threadIdx.x < 64) {
    int j = threadIdx.x;
    float4 v0, v1, vb;
    v0.x = Wih[(0 * 64 + j) * 2 + 0]; v0.y = Wih[(1 * 64 + j) * 2 + 0];
    v0.z = Wih[(2 * 64 + j) * 2 + 0]; v0.w = Wih[(3 * 64 + j) * 2 + 0];
    v1.x = Wih[(0 * 64 + j) * 2 + 1]; v1.y = Wih[(1 * 64 + j) * 2 + 1];
    v1.z = Wih[(2 * 64 + j) * 2 + 1]; v1.w = Wih[(3 * 64 + j) * 2 + 1];
    vb.x = bih[0 * 64 + j] + bhh[0 * 64 + j]; vb.y = bih[1 * 64 + j] + bhh[1 * 64 + j];
    vb.z = bih[2 * 64 + j] + bhh[2 * 64 + j]; vb.w = bih[3 * 64 + j] + bhh[3 * 64 + j];
    pack[4096 + j] = v0; pack[4160 + j] = v1; pack[4224 + j] = vb;
  }
}

// Prep: decoder fused weights W = Wih_d + Whh_d (input == hidden), transposed:
// Wd[k*128+j] = {W[g*128+j][k]}_g ; fused bias bd4[j].
__global__ void prep_dec_kernel(const float* __restrict__ Wih, const float* __restrict__ Whh,
                                const float* __restrict__ bih, const float* __restrict__ bhh,
                                float* __restrict__ wsf) {
  int idx = blockIdx.x * 256 + threadIdx.x;  // 16384 total
  int k = idx >> 7, j = idx & 127;
  float4 v;
  v.x = Wih[(0 * 128 + j) * 128 + k] + Whh[(0 * 128 + j) * 128 + k];
  v.y = Wih[(1 * 128 + j) * 128 + k] + Whh[(1 * 128 + j) * 128 + k];
  v.z = Wih[(2 * 128 + j) * 128 + k] + Whh[(2 * 128 + j) * 128 + k];
  v.w = Wih[(3 * 128 + j) * 128 + k] + Whh[(3 * 128 + j) * 128 + k];
  ((float4*)(wsf + OFF_WD))[idx] = v;
  if (blockIdx.x == 0 && threadIdx.x < 128) {
    int jj = threadIdx.x;
    float4 vb;
    vb.x = bih[0 * 128 + jj] + bhh[0 * 128 + jj];
    vb.y = bih[1 * 128 + jj] + bhh[1 * 128 + jj];
    vb.z = bih[2 * 128 + jj] + bhh[2 * 128 + jj];
    vb.w = bih[3 * 128 + jj] + bhh[3 * 128 + jj];
    ((float4*)(wsf + OFF_WD + 65536))[jj] = vb;
  }
}

// ---------------------------------------------------------------------------
// Encoder: block = 256 thr = 4 waves, wave owns 4 sequences; lane j = unit j.
// h lives in registers, broadcast via v_readlane -> no barriers in recurrence.
// Blocks [0,128) agent, [128,2176) neighbour.
// ---------------------------------------------------------------------------
__global__ __launch_bounds__(256, 2) void enc_kernel(
    const float* __restrict__ xA, const float* __restrict__ xN,
    const float4* __restrict__ packA, const float4* __restrict__ packN,
    float* __restrict__ outA, float* __restrict__ outN) {
  __shared__ float4 sW[4096];  // 64 KiB: [k][j] = {w_i,w_f,w_g,w_o}
  const int tid = threadIdx.x;
  const int j = tid & 63, sg = tid >> 6;
  const int nb = blockIdx.x;
  const bool isA = nb < 128;
  const float* xsrc = isA ? xA : xN;
  const float4* pack = isA ? packA : packN;
  float* outp = isA ? outA : outN;
  const int seqBase = (isA ? nb : nb - 128) * 16;

  for (int idx = tid; idx < 4096; idx += 256) sW[idx] = pack[idx];
  const float4 wi0 = pack[4096 + j];
  const float4 wi1 = pack[4160 + j];
  const float4 b4  = pack[4224 + j];
  __syncthreads();

  const int s0 = seqBase + sg * 4;
  const float* xp = xsrc + (size_t)s0 * (T_SEQ * 2);

  float h0r = 0.f, h1r = 0.f, h2r = 0.f, h3r = 0.f;
  float c0 = 0.f, c1 = 0.f, c2 = 0.f, c3 = 0.f;

  for (int t = 0; t < T_SEQ; ++t) {
    const float x00 = xp[0 * 100 + 2 * t], x01 = xp[0 * 100 + 2 * t + 1];
    const float x10 = xp[1 * 100 + 2 * t], x11 = xp[1 * 100 + 2 * t + 1];
    const float x20 = xp[2 * 100 + 2 * t], x21 = xp[2 * 100 + 2 * t + 1];
    const float x30 = xp[3 * 100 + 2 * t], x31 = xp[3 * 100 + 2 * t + 1];
    float4 a0 = axpy(axpy(b4, wi0, x00), wi1, x01);
    float4 a1 = axpy(axpy(b4, wi0, x10), wi1, x11);
    float4 a2 = axpy(axpy(b4, wi0, x20), wi1, x21);
    float4 a3 = axpy(axpy(b4, wi0, x30), wi1, x31);
#pragma unroll
    for (int k = 0; k < 64; ++k) {
      const float4 w = sW[(k << 6) + j];
      a0 = axpy(a0, w, rlf(h0r, k));
      a1 = axpy(a1, w, rlf(h1r, k));
      a2 = axpy(a2, w, rlf(h2r, k));
      a3 = axpy(a3, w, rlf(h3r, k));
    }
    c0 = sigf(a0.y) * c0 + sigf(a0.x) * tanhf_fast(a0.z); h0r = sigf(a0.w) * tanhf_fast(c0);
    c1 = sigf(a1.y) * c1 + sigf(a1.x) * tanhf_fast(a1.z); h1r = sigf(a1.w) * tanhf_fast(c1);
    c2 = sigf(a2.y) * c2 + sigf(a2.x) * tanhf_fast(a2.z); h2r = sigf(a2.w) * tanhf_fast(c2);
    c3 = sigf(a3.y) * c3 + sigf(a3.x) * tanhf_fast(a3.z); h3r = sigf(a3.w) * tanhf_fast(c3);
  }
  outp[(size_t)(s0 + 0) * 64 + j] = h0r;
  outp[(size_t)(s0 + 1) * 64 + j] = h1r;
  outp[(size_t)(s0 + 2) * 64 + j] = h2r;
  outp[(size_t)(s0 + 3) * 64 + j] = h3r;
}

// Masked neighbour max-pool + concat -> h0 [B,128]
__global__ void hmax_kernel(const float* __restrict__ aemb, const float* __restrict__ nenc,
                            const int* __restrict__ cnts, float* __restrict__ h0) {
  const int idx = blockIdx.x * 256 + threadIdx.x;  // 2048*64
  const int b = idx >> 6, j = idx & 63;
  h0[(size_t)b * 128 + j] = aemb[(size_t)b * 64 + j];
  const int cnt = cnts[b];
  float m = -1e30f;
  for (int n = 0; n < cnt; ++n) m = fmaxf(m, nenc[((size_t)(b * NMAX + n)) * 64 + j]);
  h0[(size_t)b * 128 + 64 + j] = (cnt > 0) ? m : 0.f;
}

// ---------------------------------------------------------------------------
// Decoder: wave owns 8 sequences; lane j holds units j and j+64 of h/c.
// Weights streamed from L2 (256 KiB hot set shared by all blocks).
// ---------------------------------------------------------------------------
__global__ __launch_bounds__(256, 2) void dec_kernel(
    const float4* __restrict__ Wd, const float4* __restrict__ bd4,
    const float* __restrict__ h0, const float* __restrict__ Wpos,
    const float* __restrict__ bpos, float* __restrict__ out) {
  const int lane = threadIdx.x & 63, wv = threadIdx.x >> 6;
  const int s0 = blockIdx.x * 32 + wv * 8;
  const float4 blo = bd4[lane], bhi = bd4[64 + lane];
  float hLo[8], hHi[8], cLo[8], cHi[8];
#pragma unroll
  for (int s = 0; s < 8; ++s) {
    hLo[s] = h0[(size_t)(s0 + s) * 128 + lane];
    hHi[s] = h0[(size_t)(s0 + s) * 128 + 64 + lane];
    cLo[s] = 0.f; cHi[s] = 0.f;
  }
  const float wp0l = Wpos[lane], wp0h = Wpos[64 + lane];
  const float wp1l = Wpos[128 + lane], wp1h = Wpos[192 + lane];
  const float bp0 = bpos[0], bp1 = bpos[1];

  for (int t = 0; t < PRED_STEPS; ++t) {
    float4 aLo[8], aHi[8];
#pragma unroll
    for (int s = 0; s < 8; ++s) { aLo[s] = blo; aHi[s] = bhi; }
#pragma unroll 4
    for (int k = 0; k < 64; ++k) {
      const float4 wlo = Wd[(k << 7) + lane];
      const float4 whi = Wd[(k << 7) + 64 + lane];
#pragma unroll
      for (int s = 0; s < 8; ++s) {
        const float hk = rlf(hLo[s], k);
        aLo[s] = axpy(aLo[s], wlo, hk);
        aHi[s] = axpy(aHi[s], whi, hk);
      }
    }
#pragma unroll 4
    for (int k = 0; k < 64; ++k) {
      const float4 wlo = Wd[((64 + k) << 7) + lane];
      const float4 whi = Wd[((64 + k) << 7) + 64 + lane];
#pragma unroll
      for (int s = 0; s < 8; ++s) {
        const float hk = rlf(hHi[s], k);
        aLo[s] = axpy(aLo[s], wlo, hk);
        aHi[s] = axpy(aHi[s], whi, hk);
      }
    }
#pragma unroll
    for (int s = 0; s < 8; ++s) {
      cLo[s] = sigf(aLo[s].y) * cLo[s] + sigf(aLo[s].x) * tanhf_fast(aLo[s].z);
      hLo[s] = sigf(aLo[s].w) * tanhf_fast(cLo[s]);
      cHi[s] = sigf(aHi[s].y) * cHi[s] + sigf(aHi[s].x) * tanhf_fast(aHi[s].z);
      hHi[s] = sigf(aHi[s].w) * tanhf_fast(cHi[s]);
    }
#pragma unroll
    for (int s = 0; s < 8; ++s) {
      float p0 = hLo[s] * wp0l + hHi[s] * wp0h;
      float p1 = hLo[s] * wp1l + hHi[s] * wp1h;
#pragma unroll
      for (int off = 32; off > 0; off >>= 1) {
        p0 += __shfl_xor(p0, off, 64);
        p1 += __shfl_xor(p1, off, 64);
      }
      if (lane == 0) {
        out[(size_t)(s0 + s) * (PRED_STEPS * 2) + t * 2 + 0] = p0 + bp0;
        out[(size_t)(s0 + s) * (PRED_STEPS * 2) + t * 2 + 1] = p1 + bp1;
      }
    }
  }
}

extern "C" void kernel_launch(void* const* d_in, const int* in_sizes, int n_in,
                              void* d_out, int out_size, void* d_ws, size_t ws_size,
                              hipStream_t stream) {
  (void)in_sizes; (void)n_in; (void)out_size; (void)ws_size;
  const float* xA    = (const float*)d_in[0];
  const float* xN    = (const float*)d_in[1];
  const int*   cnts  = (const int*)d_in[2];
  const float* Wih_a = (const float*)d_in[3];
  const float* Whh_a = (const float*)d_in[4];
  const float* bih_a = (const float*)d_in[5];
  const float* bhh_a = (const float*)d_in[6];
  const float* Wih_n = (const float*)d_in[7];
  const float* Whh_n = (const float*)d_in[8];
  const float* bih_n = (const float*)d_in[9];
  const float* bhh_n = (const float*)d_in[10];
  const float* Wih_d = (const float*)d_in[11];
  const float* Whh_d = (const float*)d_in[12];
  const float* bih_d = (const float*)d_in[13];
  const float* bhh_d = (const float*)d_in[14];
  const float* Wpos  = (const float*)d_in[15];
  const float* bpos  = (const float*)d_in[16];
  float* out = (float*)d_out;
  float* wsf = (float*)d_ws;

  prep_enc_kernel<<<2, 256, 0, stream>>>(Wih_a, Whh_a, bih_a, bhh_a,
                                         Wih_n, Whh_n, bih_n, bhh_n, wsf);
  prep_dec_kernel<<<64, 256, 0, stream>>>(Wih_d, Whh_d, bih_d, bhh_d, wsf);
  enc_kernel<<<2176, 256, 0, stream>>>(xA, xN,
                                       (const float4*)(wsf + OFF_WA),
                                       (const float4*)(wsf + OFF_WN),
                                       wsf + OFF_AEMB, wsf + OFF_NENC);
  hmax_kernel<<<512, 256, 0, stream>>>(wsf + OFF_AEMB, wsf + OFF_NENC, cnts, wsf + OFF_H0);
  dec_kernel<<<64, 256, 0, stream>>>((const float4*)(wsf + OFF_WD),
                                     (const float4*)(wsf + OFF_WD + 65536),
                                     wsf + OFF_H0, Wpos, bpos, out);
}

// Round 2
// 1714.462 us; speedup vs baseline: 2.4442x; 2.4442x over previous
//
#include <hip/hip_runtime.h>

// ---------------------------------------------------------------------------
// Social LSTM model, fp32.
//   enc:  LSTM(2->64), T=50, agent (2048 seqs) + neighbours (32768 seqs)
//   pool: masked max over valid neighbours, concat -> h0 [2048,128]
//   dec:  LSTMCell(128->128) fed its own h, 30 steps, pred = h@Wpos.T + bpos
//
// R1 changes vs R0:
//  - enc: bounded unroll (4) to stop scheduler hoisting 64 ds_read_b128
//    results past the 128-VGPR budget (R0 showed 10.8 GB HBM scratch
//    traffic = whole kernel duration). 512-thr blocks (8 waves share one
//    64 KiB sW copy -> 16 waves/CU), 8 seqs/wave (32 FMA per ds_read).
//  - dec: split-K across 4 waves/block, 8 seqs/block, 256 blocks (1/CU).
//    h + partial-gate reduction via LDS, 2 barriers/step. Weights stream
//    from L2 once per block per step (2 GB total).
// ---------------------------------------------------------------------------

#define H_ENC 64
#define H_DEC 128
#define T_SEQ 50
#define PRED_STEPS 30
#define B_SZ 2048
#define NMAX 16

// ws layout (float offsets)
static constexpr size_t OFF_AEMB = 0;                       // 2048*64
static constexpr size_t OFF_NENC = 131072;                  // 32768*64
static constexpr size_t OFF_H0   = 2228224;                 // 2048*128
static constexpr size_t OFF_WA   = 2490368;                 // 4096 f4 W + 64 f4 wi0 + 64 f4 wi1 + 64 f4 b
static constexpr size_t OFF_WN   = 2507520;
static constexpr size_t OFF_WD   = 2524672;                 // 16384 f4 + 128 f4 bias

__device__ __forceinline__ float rlf(float v, int l) {
  return __uint_as_float((unsigned)__builtin_amdgcn_readlane((int)__float_as_uint(v), l));
}
__device__ __forceinline__ float frcp(float x) { return __builtin_amdgcn_rcpf(x); }
__device__ __forceinline__ float sigf(float x) { return frcp(1.f + __expf(-x)); }
__device__ __forceinline__ float tanhf_fast(float x) {
  float ax = fabsf(x);
  float t = __expf(-2.f * ax);
  float r = 1.f - 2.f * t * frcp(1.f + t);
  return copysignf(r, x);
}
__device__ __forceinline__ float4 axpy(float4 a, float4 w, float s) {
  a.x = fmaf(w.x, s, a.x); a.y = fmaf(w.y, s, a.y);
  a.z = fmaf(w.z, s, a.z); a.w = fmaf(w.w, s, a.w);
  return a;
}

// ---------------------------------------------------------------------------
// Prep: pack encoder weights.  pack[k*64+j] = {Whh[g*64+j][k]}_{g=0..3},
// then wi0/wi1 (input cols) and fused bias, one float4 per unit j.
// ---------------------------------------------------------------------------
__global__ void prep_enc_kernel(const float* __restrict__ Wih_a, const float* __restrict__ Whh_a,
                                const float* __restrict__ bih_a, const float* __restrict__ bhh_a,
                                const float* __restrict__ Wih_n, const float* __restrict__ Whh_n,
                                const float* __restrict__ bih_n, const float* __restrict__ bhh_n,
                                float* __restrict__ wsf) {
  const int which = blockIdx.x;
  const float* Wih = which ? Wih_n : Wih_a;
  const float* Whh = which ? Whh_n : Whh_a;
  const float* bih = which ? bih_n : bih_a;
  const float* bhh = which ? bhh_n : bhh_a;
  float4* pack = (float4*)(wsf + (which ? OFF_WN : OFF_WA));
  for (int idx = threadIdx.x; idx < 4096; idx += 256) {
    int k = idx >> 6, j = idx & 63;
    float4 v;
    v.x = Whh[(0 * 64 + j) * 64 + k];
    v.y = Whh[(1 * 64 + j) * 64 + k];
    v.z = Whh[(2 * 64 + j) * 64 + k];
    v.w = Whh[(3 * 64 + j) * 64 + k];
    pack[idx] = v;
  }
  if (threadIdx.x < 64) {
    int j = threadIdx.x;
    float4 v0, v1, vb;
    v0.x = Wih[(0 * 64 + j) * 2 + 0]; v0.y = Wih[(1 * 64 + j) * 2 + 0];
    v0.z = Wih[(2 * 64 + j) * 2 + 0]; v0.w = Wih[(3 * 64 + j) * 2 + 0];
    v1.x = Wih[(0 * 64 + j) * 2 + 1]; v1.y = Wih[(1 * 64 + j) * 2 + 1];
    v1.z = Wih[(2 * 64 + j) * 2 + 1]; v1.w = Wih[(3 * 64 + j) * 2 + 1];
    vb.x = bih[0 * 64 + j] + bhh[0 * 64 + j]; vb.y = bih[1 * 64 + j] + bhh[1 * 64 + j];
    vb.z = bih[2 * 64 + j] + bhh[2 * 64 + j]; vb.w = bih[3 * 64 + j] + bhh[3 * 64 + j];
    pack[4096 + j] = v0; pack[4160 + j] = v1; pack[4224 + j] = vb;
  }
}

// Prep: decoder fused weights W = Wih_d + Whh_d (input == hidden), transposed:
// Wd[k*128+j] = {W[g*128+j][k]}_g ; fused bias bd4[j].
__global__ void prep_dec_kernel(const float* __restrict__ Wih, const float* __restrict__ Whh,
                                const float* __restrict__ bih, const float* __restrict__ bhh,
                                float* __restrict__ wsf) {
  int idx = blockIdx.x * 256 + threadIdx.x;  // 16384 total
  int k = idx >> 7, j = idx & 127;
  float4 v;
  v.x = Wih[(0 * 128 + j) * 128 + k] + Whh[(0 * 128 + j) * 128 + k];
  v.y = Wih[(1 * 128 + j) * 128 + k] + Whh[(1 * 128 + j) * 128 + k];
  v.z = Wih[(2 * 128 + j) * 128 + k] + Whh[(2 * 128 + j) * 128 + k];
  v.w = Wih[(3 * 128 + j) * 128 + k] + Whh[(3 * 128 + j) * 128 + k];
  ((float4*)(wsf + OFF_WD))[idx] = v;
  if (blockIdx.x == 0 && threadIdx.x < 128) {
    int jj = threadIdx.x;
    float4 vb;
    vb.x = bih[0 * 128 + jj] + bhh[0 * 128 + jj];
    vb.y = bih[1 * 128 + jj] + bhh[1 * 128 + jj];
    vb.z = bih[2 * 128 + jj] + bhh[2 * 128 + jj];
    vb.w = bih[3 * 128 + jj] + bhh[3 * 128 + jj];
    ((float4*)(wsf + OFF_WD + 65536))[jj] = vb;
  }
}

// ---------------------------------------------------------------------------
// Encoder: block = 512 thr = 8 waves, wave owns 8 sequences; lane j = unit j.
// h in registers, broadcast via v_readlane -> no barriers in the recurrence.
// Blocks [0,32) agent, [32,544) neighbour.
// ---------------------------------------------------------------------------
__global__ __launch_bounds__(512, 4) void enc_kernel(
    const float* __restrict__ xA, const float* __restrict__ xN,
    const float4* __restrict__ packA, const float4* __restrict__ packN,
    float* __restrict__ outA, float* __restrict__ outN) {
  __shared__ float4 sW[4096];  // 64 KiB: [k][j] = {w_i,w_f,w_g,w_o}
  const int tid = threadIdx.x;
  const int j = tid & 63, wv = tid >> 6;  // 8 waves
  const int nb = blockIdx.x;
  const bool isA = nb < 32;
  const float* xsrc = isA ? xA : xN;
  const float4* pack = isA ? packA : packN;
  float* outp = isA ? outA : outN;
  const int seqBase = (isA ? nb : nb - 32) * 64;

  for (int idx = tid; idx < 4096; idx += 512) sW[idx] = pack[idx];
  const float4 wi0 = pack[4096 + j];
  const float4 wi1 = pack[4160 + j];
  const float4 b4  = pack[4224 + j];
  __syncthreads();

  const int s0 = seqBase + wv * 8;
  const float* xp = xsrc + (size_t)s0 * (T_SEQ * 2);

  float h[8], c[8];
#pragma unroll
  for (int s = 0; s < 8; ++s) { h[s] = 0.f; c[s] = 0.f; }

  for (int t = 0; t < T_SEQ; ++t) {
    float4 a[8];
#pragma unroll
    for (int s = 0; s < 8; ++s) {
      const float x0 = xp[s * 100 + 2 * t];
      const float x1 = xp[s * 100 + 2 * t + 1];
      a[s] = axpy(axpy(b4, wi0, x0), wi1, x1);
    }
    // bounded unroll: keeps in-flight ds_read results small -> no VGPR spill
#pragma unroll 4
    for (int k = 0; k < 64; ++k) {
      const float4 w = sW[(k << 6) + j];
#pragma unroll
      for (int s = 0; s < 8; ++s) a[s] = axpy(a[s], w, rlf(h[s], k));
    }
#pragma unroll
    for (int s = 0; s < 8; ++s) {
      c[s] = sigf(a[s].y) * c[s] + sigf(a[s].x) * tanhf_fast(a[s].z);
      h[s] = sigf(a[s].w) * tanhf_fast(c[s]);
    }
  }
#pragma unroll
  for (int s = 0; s < 8; ++s) outp[(size_t)(s0 + s) * 64 + j] = h[s];
}

// Masked neighbour max-pool + concat -> h0 [B,128]
__global__ void hmax_kernel(const float* __restrict__ aemb, const float* __restrict__ nenc,
                            const int* __restrict__ cnts, float* __restrict__ h0) {
  const int idx = blockIdx.x * 256 + threadIdx.x;  // 2048*64
  const int b = idx >> 6, j = idx & 63;
  h0[(size_t)b * 128 + j] = aemb[(size_t)b * 64 + j];
  const int cnt = cnts[b];
  float m = -1e30f;
  for (int n = 0; n < cnt; ++n) m = fmaxf(m, nenc[((size_t)(b * NMAX + n)) * 64 + j]);
  h0[(size_t)b * 128 + 64 + j] = (cnt > 0) ? m : 0.f;
}

// ---------------------------------------------------------------------------
// Decoder: 256 blocks (1/CU) x 256 thr (4 waves). Block owns 8 seqs.
// Wave wv owns K-slice [32wv, 32wv+32): computes partial gates for all 8
// seqs; partials reduced in LDS. Wave wv also owns seqs 2wv,2wv+1 for the
// pointwise LSTM update + pred. h lives in LDS; c in owner-wave registers.
// ---------------------------------------------------------------------------
__global__ __launch_bounds__(256, 4) void dec_kernel(
    const float4* __restrict__ Wd, const float4* __restrict__ bd4,
    const float* __restrict__ h0, const float* __restrict__ Wpos,
    const float* __restrict__ bpos, float* __restrict__ out) {
  __shared__ float4 pLo[4][8][64];   // 32 KB
  __shared__ float4 pHi[4][8][64];   // 32 KB
  __shared__ float  hLds[8][128];    // 4 KB
  const int lane = threadIdx.x & 63, wv = threadIdx.x >> 6;
  const int sBase = blockIdx.x * 8;
  const int k0 = wv * 32;
  const int sA = 2 * wv, sB = 2 * wv + 1;

  const float4 blo = bd4[lane], bhi = bd4[64 + lane];
  const float wp0l = Wpos[lane], wp0h = Wpos[64 + lane];
  const float wp1l = Wpos[128 + lane], wp1h = Wpos[192 + lane];
  const float bp0 = bpos[0], bp1 = bpos[1];

  // owner-wave state for seqs sA, sB
  float hLoA = h0[(size_t)(sBase + sA) * 128 + lane];
  float hHiA = h0[(size_t)(sBase + sA) * 128 + 64 + lane];
  float hLoB = h0[(size_t)(sBase + sB) * 128 + lane];
  float hHiB = h0[(size_t)(sBase + sB) * 128 + 64 + lane];
  float cLoA = 0.f, cHiA = 0.f, cLoB = 0.f, cHiB = 0.f;
  hLds[sA][lane] = hLoA; hLds[sA][64 + lane] = hHiA;
  hLds[sB][lane] = hLoB; hLds[sB][64 + lane] = hHiB;
  __syncthreads();

  const float4 z4 = make_float4(0.f, 0.f, 0.f, 0.f);

  for (int t = 0; t < PRED_STEPS; ++t) {
    // load this wave's h slice: lane l -> h[2si + (l>>5)][k0 + (l&31)]
    float hreg[4];
#pragma unroll
    for (int si = 0; si < 4; ++si)
      hreg[si] = hLds[2 * si + (lane >> 5)][k0 + (lane & 31)];

    float4 aLo[8], aHi[8];
#pragma unroll
    for (int s = 0; s < 8; ++s) {
      aLo[s] = (wv == 0) ? blo : z4;
      aHi[s] = (wv == 0) ? bhi : z4;
    }
#pragma unroll 2
    for (int kk = 0; kk < 32; ++kk) {
      const float4 wlo = Wd[((k0 + kk) << 7) + lane];
      const float4 whi = Wd[((k0 + kk) << 7) + 64 + lane];
#pragma unroll
      for (int s = 0; s < 8; ++s) {
        const float hv = rlf(hreg[s >> 1], ((s & 1) << 5) | kk);
        aLo[s] = axpy(aLo[s], wlo, hv);
        aHi[s] = axpy(aHi[s], whi, hv);
      }
    }
#pragma unroll
    for (int s = 0; s < 8; ++s) { pLo[wv][s][lane] = aLo[s]; pHi[wv][s][lane] = aHi[s]; }
    __syncthreads();

    // pointwise update for owner seqs sA, sB
    float4 gLoA = pLo[0][sA][lane], gHiA = pHi[0][sA][lane];
    float4 gLoB = pLo[0][sB][lane], gHiB = pHi[0][sB][lane];
#pragma unroll
    for (int w = 1; w < 4; ++w) {
      float4 q;
      q = pLo[w][sA][lane]; gLoA.x += q.x; gLoA.y += q.y; gLoA.z += q.z; gLoA.w += q.w;
      q = pHi[w][sA][lane]; gHiA.x += q.x; gHiA.y += q.y; gHiA.z += q.z; gHiA.w += q.w;
      q = pLo[w][sB][lane]; gLoB.x += q.x; gLoB.y += q.y; gLoB.z += q.z; gLoB.w += q.w;
      q = pHi[w][sB][lane]; gHiB.x += q.x; gHiB.y += q.y; gHiB.z += q.z; gHiB.w += q.w;
    }
    cLoA = sigf(gLoA.y) * cLoA + sigf(gLoA.x) * tanhf_fast(gLoA.z);
    hLoA = sigf(gLoA.w) * tanhf_fast(cLoA);
    cHiA = sigf(gHiA.y) * cHiA + sigf(gHiA.x) * tanhf_fast(gHiA.z);
    hHiA = sigf(gHiA.w) * tanhf_fast(cHiA);
    cLoB = sigf(gLoB.y) * cLoB + sigf(gLoB.x) * tanhf_fast(gLoB.z);
    hLoB = sigf(gLoB.w) * tanhf_fast(cLoB);
    cHiB = sigf(gHiB.y) * cHiB + sigf(gHiB.x) * tanhf_fast(gHiB.z);
    hHiB = sigf(gHiB.w) * tanhf_fast(cHiB);

    hLds[sA][lane] = hLoA; hLds[sA][64 + lane] = hHiA;
    hLds[sB][lane] = hLoB; hLds[sB][64 + lane] = hHiB;

    // pred = h @ Wpos.T + bpos  (2 outputs per seq)
    float p0A = hLoA * wp0l + hHiA * wp0h;
    float p1A = hLoA * wp1l + hHiA * wp1h;
    float p0B = hLoB * wp0l + hHiB * wp0h;
    float p1B = hLoB * wp1l + hHiB * wp1h;
#pragma unroll
    for (int off = 32; off > 0; off >>= 1) {
      p0A += __shfl_xor(p0A, off, 64); p1A += __shfl_xor(p1A, off, 64);
      p0B += __shfl_xor(p0B, off, 64); p1B += __shfl_xor(p1B, off, 64);
    }
    if (lane == 0) {
      out[(size_t)(sBase + sA) * (PRED_STEPS * 2) + t * 2 + 0] = p0A + bp0;
      out[(size_t)(sBase + sA) * (PRED_STEPS * 2) + t * 2 + 1] = p1A + bp1;
      out[(size_t)(sBase + sB) * (PRED_STEPS * 2) + t * 2 + 0] = p0B + bp0;
      out[(size_t)(sBase + sB) * (PRED_STEPS * 2) + t * 2 + 1] = p1B + bp1;
    }
    __syncthreads();
  }
}

extern "C" void kernel_launch(void* const* d_in, const int* in_sizes, int n_in,
                              void* d_out, int out_size, void* d_ws, size_t ws_size,
                              hipStream_t stream) {
  (void)in_sizes; (void)n_in; (void)out_size; (void)ws_size;
  const float* xA    = (const float*)d_in[0];
  const float* xN    = (const float*)d_in[1];
  const int*   cnts  = (const int*)d_in[2];
  const float* Wih_a = (const float*)d_in[3];
  const float* Whh_a = (const float*)d_in[4];
  const float* bih_a = (const float*)d_in[5];
  const float* bhh_a = (const float*)d_in[6];
  const float* Wih_n = (const float*)d_in[7];
  const float* Whh_n = (const float*)d_in[8];
  const float* bih_n = (const float*)d_in[9];
  const float* bhh_n = (const float*)d_in[10];
  const float* Wih_d = (const float*)d_in[11];
  const float* Whh_d = (const float*)d_in[12];
  const float* bih_d = (const float*)d_in[13];
  const float* bhh_d = (const float*)d_in[14];
  const float* Wpos  = (const float*)d_in[15];
  const float* bpos  = (const float*)d_in[16];
  float* out = (float*)d_out;
  float* wsf = (float*)d_ws;

  prep_enc_kernel<<<2, 256, 0, stream>>>(Wih_a, Whh_a, bih_a, bhh_a,
                                         Wih_n, Whh_n, bih_n, bhh_n, wsf);
  prep_dec_kernel<<<64, 256, 0, stream>>>(Wih_d, Whh_d, bih_d, bhh_d, wsf);
  enc_kernel<<<544, 512, 0, stream>>>(xA, xN,
                                      (const float4*)(wsf + OFF_WA),
                                      (const float4*)(wsf + OFF_WN),
                                      wsf + OFF_AEMB, wsf + OFF_NENC);
  hmax_kernel<<<512, 256, 0, stream>>>(wsf + OFF_AEMB, wsf + OFF_NENC, cnts, wsf + OFF_H0);
  dec_kernel<<<256, 256, 0, stream>>>((const float4*)(wsf + OFF_WD),
                                      (const float4*)(wsf + OFF_WD + 65536),
                                      wsf + OFF_H0, Wpos, bpos, out);
}

// Round 3
// 1274.270 us; speedup vs baseline: 3.2886x; 1.3454x over previous
//
#include <hip/hip_runtime.h>
#include <stdint.h>

// ---------------------------------------------------------------------------
// Social LSTM model, fp32 with packed-fp32 FMA (v_pk_fma_f32).
//   enc:  LSTM(2->64), T=50: phase1 = 32768 neighbour seqs (8/wave, exact),
//         phase2 = 2048 agent seqs (blocks<256 reload LDS weights, 1/wave).
//   pool: masked max over valid neighbours, concat -> h0 [2048,128]
//   dec:  LSTMCell(128->128) self-fed, 30 steps, split-K over 4 waves.
// Gates held as packed pairs {i,f},{g,o}; h broadcast via v_readlane ->
// SGPR pair consumed by v_pk_fma_f32 op_sel_hi:[1,0,1] (scalar-broadcast).
// Grid = 512 blocks x 512 thr = exactly 2 blocks/CU -> no dispatch tail.
// ---------------------------------------------------------------------------

#define T_SEQ 50
#define PRED_STEPS 30
#define NMAX 16

typedef float v2f __attribute__((ext_vector_type(2)));
typedef float v4f __attribute__((ext_vector_type(4)));

// ws layout (float offsets) -- ~10.4 MB total (fits proven ws size)
static constexpr size_t OFF_AEMB = 0;          // 2048*64
static constexpr size_t OFF_NENC = 131072;     // 32768*64
static constexpr size_t OFF_H0   = 2228224;    // 2048*128
static constexpr size_t OFF_WA   = 2490368;    // 4288 v4f
static constexpr size_t OFF_WN   = 2507520;    // 4288 v4f
static constexpr size_t OFF_WD   = 2524672;    // 16384 v4f + 128 v4f bias

__device__ __forceinline__ float frcp(float x) { return __builtin_amdgcn_rcpf(x); }
__device__ __forceinline__ float sigf(float x) { return frcp(1.f + __expf(-x)); }
__device__ __forceinline__ float tanhf_fast(float x) {
  float ax = fabsf(x);
  float t = __expf(-2.f * ax);
  float r = 1.f - 2.f * t * frcp(1.f + t);
  return copysignf(r, x);
}

// acc.{lo,hi} += w.{lo,hi} * lo32(hb)   (scalar broadcast from SGPR pair)
__device__ __forceinline__ void pk_fma_s(v2f& acc, v2f w, uint64_t hb) {
  asm("v_pk_fma_f32 %0, %1, %2, %0 op_sel_hi:[1,0,1]"
      : "+v"(acc) : "v"(w), "s"(hb));
}
// acc.{lo,hi} += w.{lo,hi} * x2.lo      (broadcast word0 of VGPR pair)
__device__ __forceinline__ void pk_fma_v0(v2f& acc, v2f w, v2f x2) {
  asm("v_pk_fma_f32 %0, %1, %2, %0 op_sel_hi:[1,0,1]"
      : "+v"(acc) : "v"(w), "v"(x2));
}
// acc.{lo,hi} += w.{lo,hi} * x2.hi      (broadcast word1 of VGPR pair)
__device__ __forceinline__ void pk_fma_v1(v2f& acc, v2f w, v2f x2) {
  asm("v_pk_fma_f32 %0, %1, %2, %0 op_sel:[0,1,0] op_sel_hi:[1,1,1]"
      : "+v"(acc) : "v"(w), "v"(x2));
}
__device__ __forceinline__ uint64_t bcast(float v, int l) {
  return (uint64_t)(uint32_t)__builtin_amdgcn_readlane((int)__float_as_uint(v), l);
}

// ---------------------------------------------------------------------------
// Prep: pack encoder weights.  pack[k*64+j] = {Whh[g*64+j][k]}_{g=i,f,g,o},
// then wi0/wi1 (input cols) and fused bias, one v4f per unit j.
// ---------------------------------------------------------------------------
__global__ void prep_enc_kernel(const float* __restrict__ Wih_a, const float* __restrict__ Whh_a,
                                const float* __restrict__ bih_a, const float* __restrict__ bhh_a,
                                const float* __restrict__ Wih_n, const float* __restrict__ Whh_n,
                                const float* __restrict__ bih_n, const float* __restrict__ bhh_n,
                                float* __restrict__ wsf) {
  const int which = blockIdx.x;
  const float* Wih = which ? Wih_n : Wih_a;
  const float* Whh = which ? Whh_n : Whh_a;
  const float* bih = which ? bih_n : bih_a;
  const float* bhh = which ? bhh_n : bhh_a;
  v4f* pack = (v4f*)(wsf + (which ? OFF_WN : OFF_WA));
  for (int idx = threadIdx.x; idx < 4096; idx += 256) {
    int k = idx >> 6, j = idx & 63;
    v4f v;
    v.x = Whh[(0 * 64 + j) * 64 + k];
    v.y = Whh[(1 * 64 + j) * 64 + k];
    v.z = Whh[(2 * 64 + j) * 64 + k];
    v.w = Whh[(3 * 64 + j) * 64 + k];
    pack[idx] = v;
  }
  if (threadIdx.x < 64) {
    int j = threadIdx.x;
    v4f v0, v1, vb;
    v0.x = Wih[(0 * 64 + j) * 2 + 0]; v0.y = Wih[(1 * 64 + j) * 2 + 0];
    v0.z = Wih[(2 * 64 + j) * 2 + 0]; v0.w = Wih[(3 * 64 + j) * 2 + 0];
    v1.x = Wih[(0 * 64 + j) * 2 + 1]; v1.y = Wih[(1 * 64 + j) * 2 + 1];
    v1.z = Wih[(2 * 64 + j) * 2 + 1]; v1.w = Wih[(3 * 64 + j) * 2 + 1];
    vb.x = bih[0 * 64 + j] + bhh[0 * 64 + j]; vb.y = bih[1 * 64 + j] + bhh[1 * 64 + j];
    vb.z = bih[2 * 64 + j] + bhh[2 * 64 + j]; vb.w = bih[3 * 64 + j] + bhh[3 * 64 + j];
    pack[4096 + j] = v0; pack[4160 + j] = v1; pack[4224 + j] = vb;
  }
}

// Prep: decoder fused W = Wih_d + Whh_d, transposed: Wd[k*128+j] = {W[g][j][k]}_g
__global__ void prep_dec_kernel(const float* __restrict__ Wih, const float* __restrict__ Whh,
                                const float* __restrict__ bih, const float* __restrict__ bhh,
                                float* __restrict__ wsf) {
  int idx = blockIdx.x * 256 + threadIdx.x;  // 16384 total
  int k = idx >> 7, j = idx & 127;
  v4f v;
  v.x = Wih[(0 * 128 + j) * 128 + k] + Whh[(0 * 128 + j) * 128 + k];
  v.y = Wih[(1 * 128 + j) * 128 + k] + Whh[(1 * 128 + j) * 128 + k];
  v.z = Wih[(2 * 128 + j) * 128 + k] + Whh[(2 * 128 + j) * 128 + k];
  v.w = Wih[(3 * 128 + j) * 128 + k] + Whh[(3 * 128 + j) * 128 + k];
  ((v4f*)(wsf + OFF_WD))[idx] = v;
  if (blockIdx.x == 0 && threadIdx.x < 128) {
    int jj = threadIdx.x;
    v4f vb;
    vb.x = bih[0 * 128 + jj] + bhh[0 * 128 + jj];
    vb.y = bih[1 * 128 + jj] + bhh[1 * 128 + jj];
    vb.z = bih[2 * 128 + jj] + bhh[2 * 128 + jj];
    vb.w = bih[3 * 128 + jj] + bhh[3 * 128 + jj];
    ((v4f*)(wsf + OFF_WD + 65536))[jj] = vb;
  }
}

// ---------------------------------------------------------------------------
// Encoder. 512 blocks x 512 thr (8 waves). lane j = unit j.
// Phase 1: wave gw owns neighbour seqs [8gw, 8gw+8)  (4096*8 = 32768 exact).
// Phase 2: blocks < 256 reload sW with agent pack; wave gw owns agent seq gw.
// ---------------------------------------------------------------------------
__global__ __launch_bounds__(512, 4) void enc_kernel(
    const float* __restrict__ xA, const float* __restrict__ xN,
    const v4f* __restrict__ packA, const v4f* __restrict__ packN,
    float* __restrict__ outA, float* __restrict__ outN) {
  __shared__ v4f sW[4096];  // 64 KiB: [k][j] = {w_i,w_f,w_g,w_o}
  const int tid = threadIdx.x;
  const int j = tid & 63, wv = tid >> 6;
  const int gw = blockIdx.x * 8 + wv;  // global wave id, 0..4095

  for (int idx = tid; idx < 4096; idx += 512) sW[idx] = packN[idx];
  const v4f wi0 = packN[4096 + j];
  const v4f wi1 = packN[4160 + j];
  const v4f b4  = packN[4224 + j];
  const v2f wi0if = __builtin_shufflevector(wi0, wi0, 0, 1);
  const v2f wi0go = __builtin_shufflevector(wi0, wi0, 2, 3);
  const v2f wi1if = __builtin_shufflevector(wi1, wi1, 0, 1);
  const v2f wi1go = __builtin_shufflevector(wi1, wi1, 2, 3);
  const v2f bif   = __builtin_shufflevector(b4, b4, 0, 1);
  const v2f bgo   = __builtin_shufflevector(b4, b4, 2, 3);
  __syncthreads();

  // ---- phase 1: 8 neighbour sequences ----
  {
    const int s0 = gw * 8;
    const v2f* xp = (const v2f*)(xN + (size_t)s0 * (T_SEQ * 2));
    float h[8], c[8];
#pragma unroll
    for (int s = 0; s < 8; ++s) { h[s] = 0.f; c[s] = 0.f; }

    for (int t = 0; t < T_SEQ; ++t) {
      v2f xv[8];
#pragma unroll
      for (int s = 0; s < 8; ++s) xv[s] = xp[s * T_SEQ + t];
      v2f aif[8], ago[8];
#pragma unroll
      for (int s = 0; s < 8; ++s) {
        aif[s] = bif; ago[s] = bgo;
        pk_fma_v0(aif[s], wi0if, xv[s]); pk_fma_v0(ago[s], wi0go, xv[s]);
        pk_fma_v1(aif[s], wi1if, xv[s]); pk_fma_v1(ago[s], wi1go, xv[s]);
      }
#pragma unroll 2
      for (int k = 0; k < 64; ++k) {
        const v4f w4 = sW[(k << 6) + j];
        const v2f wif = __builtin_shufflevector(w4, w4, 0, 1);
        const v2f wgo = __builtin_shufflevector(w4, w4, 2, 3);
#pragma unroll
        for (int s = 0; s < 8; ++s) {
          const uint64_t hb = bcast(h[s], k);
          pk_fma_s(aif[s], wif, hb);
          pk_fma_s(ago[s], wgo, hb);
        }
      }
#pragma unroll
      for (int s = 0; s < 8; ++s) {
        c[s] = sigf(aif[s].y) * c[s] + sigf(aif[s].x) * tanhf_fast(ago[s].x);
        h[s] = sigf(ago[s].y) * tanhf_fast(c[s]);
      }
    }
    float* op = outN + (size_t)s0 * 64 + j;
#pragma unroll
    for (int s = 0; s < 8; ++s) op[s * 64] = h[s];
  }

  // ---- phase 2: agent sequences on blocks < 256 (wave gw -> agent seq gw) ----
  if (blockIdx.x < 256) {
    __syncthreads();
    for (int idx = tid; idx < 4096; idx += 512) sW[idx] = packA[idx];
    const v4f awi0 = packA[4096 + j];
    const v4f awi1 = packA[4160 + j];
    const v4f ab4  = packA[4224 + j];
    const v2f awi0if = __builtin_shufflevector(awi0, awi0, 0, 1);
    const v2f awi0go = __builtin_shufflevector(awi0, awi0, 2, 3);
    const v2f awi1if = __builtin_shufflevector(awi1, awi1, 0, 1);
    const v2f awi1go = __builtin_shufflevector(awi1, awi1, 2, 3);
    const v2f abif   = __builtin_shufflevector(ab4, ab4, 0, 1);
    const v2f abgo   = __builtin_shufflevector(ab4, ab4, 2, 3);
    __syncthreads();

    const v2f* xp = (const v2f*)(xA + (size_t)gw * (T_SEQ * 2));
    float h = 0.f, c = 0.f;
    for (int t = 0; t < T_SEQ; ++t) {
      const v2f xv = xp[t];
      v2f aif = abif, ago = abgo;
      pk_fma_v0(aif, awi0if, xv); pk_fma_v0(ago, awi0go, xv);
      pk_fma_v1(aif, awi1if, xv); pk_fma_v1(ago, awi1go, xv);
#pragma unroll 4
      for (int k = 0; k < 64; ++k) {
        const v4f w4 = sW[(k << 6) + j];
        const v2f wif = __builtin_shufflevector(w4, w4, 0, 1);
        const v2f wgo = __builtin_shufflevector(w4, w4, 2, 3);
        const uint64_t hb = bcast(h, k);
        pk_fma_s(aif, wif, hb);
        pk_fma_s(ago, wgo, hb);
      }
      c = sigf(aif.y) * c + sigf(aif.x) * tanhf_fast(ago.x);
      h = sigf(ago.y) * tanhf_fast(c);
    }
    outA[(size_t)gw * 64 + j] = h;
  }
}

// Masked neighbour max-pool + concat -> h0 [B,128]
__global__ void hmax_kernel(const float* __restrict__ aemb, const float* __restrict__ nenc,
                            const int* __restrict__ cnts, float* __restrict__ h0) {
  const int idx = blockIdx.x * 256 + threadIdx.x;  // 2048*64
  const int b = idx >> 6, j = idx & 63;
  h0[(size_t)b * 128 + j] = aemb[(size_t)b * 64 + j];
  const int cnt = cnts[b];
  float m = -1e30f;
  for (int n = 0; n < cnt; ++n) m = fmaxf(m, nenc[((size_t)(b * NMAX + n)) * 64 + j]);
  h0[(size_t)b * 128 + 64 + j] = (cnt > 0) ? m : 0.f;
}

// ---------------------------------------------------------------------------
// Decoder: 256 blocks (1/CU) x 256 thr (4 waves). Block owns 8 seqs.
// Wave wv owns K-slice [32wv,32wv+32); partial gates reduced in LDS.
// Wave wv owns seqs 2wv,2wv+1 for the pointwise update + pred.
// ---------------------------------------------------------------------------
__global__ __launch_bounds__(256, 4) void dec_kernel(
    const v4f* __restrict__ Wd, const v4f* __restrict__ bd4,
    const float* __restrict__ h0, const float* __restrict__ Wpos,
    const float* __restrict__ bpos, float* __restrict__ out) {
  __shared__ v4f pLo[4][8][64];   // 32 KB
  __shared__ v4f pHi[4][8][64];   // 32 KB
  __shared__ float hLds[8][128];  // 4 KB
  const int lane = threadIdx.x & 63, wv = threadIdx.x >> 6;
  const int sBase = blockIdx.x * 8;
  const int k0 = wv * 32;
  const int sA = 2 * wv, sB = 2 * wv + 1;

  const v4f blo4 = bd4[lane], bhi4 = bd4[64 + lane];
  const v2f bloIf = __builtin_shufflevector(blo4, blo4, 0, 1);
  const v2f bloGo = __builtin_shufflevector(blo4, blo4, 2, 3);
  const v2f bhiIf = __builtin_shufflevector(bhi4, bhi4, 0, 1);
  const v2f bhiGo = __builtin_shufflevector(bhi4, bhi4, 2, 3);
  const float wp0l = Wpos[lane], wp0h = Wpos[64 + lane];
  const float wp1l = Wpos[128 + lane], wp1h = Wpos[192 + lane];
  const float bp0 = bpos[0], bp1 = bpos[1];

  float hLoA = h0[(size_t)(sBase + sA) * 128 + lane];
  float hHiA = h0[(size_t)(sBase + sA) * 128 + 64 + lane];
  float hLoB = h0[(size_t)(sBase + sB) * 128 + lane];
  float hHiB = h0[(size_t)(sBase + sB) * 128 + 64 + lane];
  float cLoA = 0.f, cHiA = 0.f, cLoB = 0.f, cHiB = 0.f;
  hLds[sA][lane] = hLoA; hLds[sA][64 + lane] = hHiA;
  hLds[sB][lane] = hLoB; hLds[sB][64 + lane] = hHiB;
  __syncthreads();

  const v2f z2 = {0.f, 0.f};

  for (int t = 0; t < PRED_STEPS; ++t) {
    float hreg[4];
#pragma unroll
    for (int si = 0; si < 4; ++si)
      hreg[si] = hLds[2 * si + (lane >> 5)][k0 + (lane & 31)];

    v2f aLoIf[8], aLoGo[8], aHiIf[8], aHiGo[8];
#pragma unroll
    for (int s = 0; s < 8; ++s) {
      aLoIf[s] = (wv == 0) ? bloIf : z2; aLoGo[s] = (wv == 0) ? bloGo : z2;
      aHiIf[s] = (wv == 0) ? bhiIf : z2; aHiGo[s] = (wv == 0) ? bhiGo : z2;
    }
#pragma unroll 2
    for (int kk = 0; kk < 32; ++kk) {
      const v4f wlo4 = Wd[((k0 + kk) << 7) + lane];
      const v4f whi4 = Wd[((k0 + kk) << 7) + 64 + lane];
      const v2f wloIf = __builtin_shufflevector(wlo4, wlo4, 0, 1);
      const v2f wloGo = __builtin_shufflevector(wlo4, wlo4, 2, 3);
      const v2f whiIf = __builtin_shufflevector(whi4, whi4, 0, 1);
      const v2f whiGo = __builtin_shufflevector(whi4, whi4, 2, 3);
#pragma unroll
      for (int s = 0; s < 8; ++s) {
        const uint64_t hb = bcast(hreg[s >> 1], ((s & 1) << 5) | kk);
        pk_fma_s(aLoIf[s], wloIf, hb); pk_fma_s(aLoGo[s], wloGo, hb);
        pk_fma_s(aHiIf[s], whiIf, hb); pk_fma_s(aHiGo[s], whiGo, hb);
      }
    }
#pragma unroll
    for (int s = 0; s < 8; ++s) {
      pLo[wv][s][lane] = __builtin_shufflevector(aLoIf[s], aLoGo[s], 0, 1, 2, 3);
      pHi[wv][s][lane] = __builtin_shufflevector(aHiIf[s], aHiGo[s], 0, 1, 2, 3);
    }
    __syncthreads();

    v4f gLoA = pLo[0][sA][lane], gHiA = pHi[0][sA][lane];
    v4f gLoB = pLo[0][sB][lane], gHiB = pHi[0][sB][lane];
#pragma unroll
    for (int w = 1; w < 4; ++w) {
      gLoA += pLo[w][sA][lane]; gHiA += pHi[w][sA][lane];
      gLoB += pLo[w][sB][lane]; gHiB += pHi[w][sB][lane];
    }
    cLoA = sigf(gLoA.y) * cLoA + sigf(gLoA.x) * tanhf_fast(gLoA.z);
    hLoA = sigf(gLoA.w) * tanhf_fast(cLoA);
    cHiA = sigf(gHiA.y) * cHiA + sigf(gHiA.x) * tanhf_fast(gHiA.z);
    hHiA = sigf(gHiA.w) * tanhf_fast(cHiA);
    cLoB = sigf(gLoB.y) * cLoB + sigf(gLoB.x) * tanhf_fast(gLoB.z);
    hLoB = sigf(gLoB.w) * tanhf_fast(cLoB);
    cHiB = sigf(gHiB.y) * cHiB + sigf(gHiB.x) * tanhf_fast(gHiB.z);
    hHiB = sigf(gHiB.w) * tanhf_fast(cHiB);

    hLds[sA][lane] = hLoA; hLds[sA][64 + lane] = hHiA;
    hLds[sB][lane] = hLoB; hLds[sB][64 + lane] = hHiB;

    float p0A = hLoA * wp0l + hHiA * wp0h;
    float p1A = hLoA * wp1l + hHiA * wp1h;
    float p0B = hLoB * wp0l + hHiB * wp0h;
    float p1B = hLoB * wp1l + hHiB * wp1h;
#pragma unroll
    for (int off = 32; off > 0; off >>= 1) {
      p0A += __shfl_xor(p0A, off, 64); p1A += __shfl_xor(p1A, off, 64);
      p0B += __shfl_xor(p0B, off, 64); p1B += __shfl_xor(p1B, off, 64);
    }
    if (lane == 0) {
      out[(size_t)(sBase + sA) * (PRED_STEPS * 2) + t * 2 + 0] = p0A + bp0;
      out[(size_t)(sBase + sA) * (PRED_STEPS * 2) + t * 2 + 1] = p1A + bp1;
      out[(size_t)(sBase + sB) * (PRED_STEPS * 2) + t * 2 + 0] = p0B + bp0;
      out[(size_t)(sBase + sB) * (PRED_STEPS * 2) + t * 2 + 1] = p1B + bp1;
    }
    __syncthreads();
  }
}

extern "C" void kernel_launch(void* const* d_in, const int* in_sizes, int n_in,
                              void* d_out, int out_size, void* d_ws, size_t ws_size,
                              hipStream_t stream) {
  (void)in_sizes; (void)n_in; (void)out_size; (void)ws_size;
  const float* xA    = (const float*)d_in[0];
  const float* xN    = (const float*)d_in[1];
  const int*   cnts  = (const int*)d_in[2];
  const float* Wih_a = (const float*)d_in[3];
  const float* Whh_a = (const float*)d_in[4];
  const float* bih_a = (const float*)d_in[5];
  const float* bhh_a = (const float*)d_in[6];
  const float* Wih_n = (const float*)d_in[7];
  const float* Whh_n = (const float*)d_in[8];
  const float* bih_n = (const float*)d_in[9];
  const float* bhh_n = (const float*)d_in[10];
  const float* Wih_d = (const float*)d_in[11];
  const float* Whh_d = (const float*)d_in[12];
  const float* bih_d = (const float*)d_in[13];
  const float* bhh_d = (const float*)d_in[14];
  const float* Wpos  = (const float*)d_in[15];
  const float* bpos  = (const float*)d_in[16];
  float* out = (float*)d_out;
  float* wsf = (float*)d_ws;

  prep_enc_kernel<<<2, 256, 0, stream>>>(Wih_a, Whh_a, bih_a, bhh_a,
                                         Wih_n, Whh_n, bih_n, bhh_n, wsf);
  prep_dec_kernel<<<64, 256, 0, stream>>>(Wih_d, Whh_d, bih_d, bhh_d, wsf);
  enc_kernel<<<512, 512, 0, stream>>>(xA, xN,
                                      (const v4f*)(wsf + OFF_WA),
                                      (const v4f*)(wsf + OFF_WN),
                                      wsf + OFF_AEMB, wsf + OFF_NENC);
  hmax_kernel<<<512, 256, 0, stream>>>(wsf + OFF_AEMB, wsf + OFF_NENC, cnts, wsf + OFF_H0);
  dec_kernel<<<256, 256, 0, stream>>>((const v4f*)(wsf + OFF_WD),
                                      (const v4f*)(wsf + OFF_WD + 65536),
                                      wsf + OFF_H0, Wpos, bpos, out);
}

// Round 4
// 528.088 us; speedup vs baseline: 7.9354x; 2.4130x over previous
//
#include <hip/hip_runtime.h>
#include <stdint.h>

// ---------------------------------------------------------------------------
// Social LSTM model.
//   enc (MFMA): LSTM(2->64), T=50. Block = 4 waves = 16 seqs. Per t the
//     recurrent matmul [16x64]@[64x256] runs on v_mfma_f32_16x16x32_bf16
//     with bf16x3 split (Ahi*Bhi + Ahi*Blo + Alo*Bhi) => ~fp32 accuracy.
//     Whh is register-resident per wave (hi/lo frags). h round-trips LDS
//     in a swizzle-paired hi/lo plane layout (stride 36 => conflict-free
//     ds_read_b128 A-frags, no unpack VALU). Acc init = exact fp32 input
//     projection + bias. c-state stays in registers (C-layout).
//   pool: masked max over valid neighbours, concat -> h0 [2048,128]
//   dec (pk_fma, unchanged R3): LSTMCell(128->128), split-K over 4 waves.
// ---------------------------------------------------------------------------

#define T_SEQ 50
#define PRED_STEPS 30
#define NMAX 16

typedef float v2f __attribute__((ext_vector_type(2)));
typedef float v4f __attribute__((ext_vector_type(4)));
typedef short v8s __attribute__((ext_vector_type(8)));

// ws layout (float offsets)
static constexpr size_t OFF_AEMB  = 0;          // 2048*64
static constexpr size_t OFF_NENC  = 131072;     // 32768*64
static constexpr size_t OFF_H0    = 2228224;    // 2048*128
static constexpr size_t OFF_PACKA = 2490368;    // 64 KB bf16 B-frags (agent)
static constexpr size_t OFF_PACKN = 2507520;    // 64 KB bf16 B-frags (neigh)
static constexpr size_t OFF_WD    = 2524672;    // 16384 v4f + 128 v4f bias

__device__ __forceinline__ float frcp(float x) { return __builtin_amdgcn_rcpf(x); }
__device__ __forceinline__ float sigf(float x) { return frcp(1.f + __expf(-x)); }
__device__ __forceinline__ float tanhf_fast(float x) {
  float ax = fabsf(x);
  float t = __expf(-2.f * ax);
  float r = 1.f - 2.f * t * frcp(1.f + t);
  return copysignf(r, x);
}
__device__ __forceinline__ unsigned bf16rne(float f) {  // fp32 -> bf16 bits (RNE)
  unsigned u = __float_as_uint(f);
  u += 0x7fff + ((u >> 16) & 1);
  return u >> 16;
}
__device__ __forceinline__ float bf16tof(unsigned h) { return __uint_as_float(h << 16); }

__device__ __forceinline__ v4f mfma16(v8s a, v8s b, v4f c) {
  return __builtin_amdgcn_mfma_f32_16x16x32_bf16(a, b, c, 0, 0, 0);
}

// pk helpers for the decoder (unchanged R3)
__device__ __forceinline__ void pk_fma_s(v2f& acc, v2f w, uint64_t hb) {
  asm("v_pk_fma_f32 %0, %1, %2, %0 op_sel_hi:[1,0,1]" : "+v"(acc) : "v"(w), "s"(hb));
}
__device__ __forceinline__ uint64_t bcast(float v, int l) {
  return (uint64_t)(uint32_t)__builtin_amdgcn_readlane((int)__float_as_uint(v), l);
}

// ---------------------------------------------------------------------------
// Prep: encoder Whh as MFMA B-fragments, bf16 hi/lo split.
// chunk c = ((w*4+g)*2+kh)*2+p ; within chunk, lane l holds 8 bf16:
//   B[k][n]: n = lane&15 (unit j = 16w+n within wave slice), k = (l>>4)*8+e
//   value = split_p( Whh[g*64 + 16w + (l&15)][kh*32 + (l>>4)*8 + e] )
// ---------------------------------------------------------------------------
__global__ void prep_encpack(const float* __restrict__ Whh_a, const float* __restrict__ Whh_n,
                             uint4* __restrict__ packA, uint4* __restrict__ packN) {
  const int which = blockIdx.x >> 4;
  const int idx = (blockIdx.x & 15) * 256 + threadIdx.x;  // 0..4095
  const float* Whh = which ? Whh_n : Whh_a;
  uint4* dst = which ? packN : packA;
  const int lane = idx & 63, c = idx >> 6;
  const int p = c & 1, kh = (c >> 1) & 1, g = (c >> 2) & 3, w = (c >> 4) & 3;
  const int row = g * 64 + 16 * w + (lane & 15);
  const int kb = kh * 32 + (lane >> 4) * 8;
  unsigned us[8];
#pragma unroll
  for (int e = 0; e < 8; ++e) {
    float W = Whh[row * 64 + kb + e];
    unsigned hi = bf16rne(W);
    us[e] = p ? bf16rne(W - bf16tof(hi)) : hi;
  }
  uint4 o;
  o.x = us[0] | (us[1] << 16);
  o.y = us[2] | (us[3] << 16);
  o.z = us[4] | (us[5] << 16);
  o.w = us[6] | (us[7] << 16);
  dst[c * 64 + lane] = o;
}

// Prep: decoder fused W = Wih_d + Whh_d, transposed (unchanged R3)
__global__ void prep_dec_kernel(const float* __restrict__ Wih, const float* __restrict__ Whh,
                                const float* __restrict__ bih, const float* __restrict__ bhh,
                                float* __restrict__ wsf) {
  int idx = blockIdx.x * 256 + threadIdx.x;  // 16384 total
  int k = idx >> 7, j = idx & 127;
  v4f v;
  v.x = Wih[(0 * 128 + j) * 128 + k] + Whh[(0 * 128 + j) * 128 + k];
  v.y = Wih[(1 * 128 + j) * 128 + k] + Whh[(1 * 128 + j) * 128 + k];
  v.z = Wih[(2 * 128 + j) * 128 + k] + Whh[(2 * 128 + j) * 128 + k];
  v.w = Wih[(3 * 128 + j) * 128 + k] + Whh[(3 * 128 + j) * 128 + k];
  ((v4f*)(wsf + OFF_WD))[idx] = v;
  if (blockIdx.x == 0 && threadIdx.x < 128) {
    int jj = threadIdx.x;
    v4f vb;
    vb.x = bih[0 * 128 + jj] + bhh[0 * 128 + jj];
    vb.y = bih[1 * 128 + jj] + bhh[1 * 128 + jj];
    vb.z = bih[2 * 128 + jj] + bhh[2 * 128 + jj];
    vb.w = bih[3 * 128 + jj] + bhh[3 * 128 + jj];
    ((v4f*)(wsf + OFF_WD + 65536))[jj] = vb;
  }
}

// ---------------------------------------------------------------------------
// Encoder MFMA kernel. Grid: blocks [0,2048) = neighbour (16 seqs each),
// [2048,2176) = agent. 256 thr = 4 waves.
// LDS: h planes (hi @0, lo @576), stride 36 words per seq row; x stage.
// ---------------------------------------------------------------------------
__global__ __launch_bounds__(256, 2) void enc_mfma_kernel(
    const float* __restrict__ xA, const float* __restrict__ xN,
    const v8s* __restrict__ packA, const v8s* __restrict__ packN,
    const float* __restrict__ Wih_a, const float* __restrict__ bih_a, const float* __restrict__ bhh_a,
    const float* __restrict__ Wih_n, const float* __restrict__ bih_n, const float* __restrict__ bhh_n,
    float* __restrict__ outA, float* __restrict__ outN) {
  __shared__ unsigned hpl[1152];  // hi plane [m*36+jp], lo plane +576
  __shared__ float xst[1600];     // [m][t][2]
  const int tid = threadIdx.x, lane = tid & 63, wv = tid >> 6;
  const int nb = blockIdx.x;
  const bool isA = nb >= 2048;
  const float* xsrc = isA ? xA : xN;
  const v8s* pk = isA ? packA : packN;
  const float* Wih = isA ? Wih_a : Wih_n;
  const float* bih = isA ? bih_a : bih_n;
  const float* bhh = isA ? bhh_a : bhh_n;
  float* outp = isA ? outA : outN;
  const int s0 = (isA ? nb - 2048 : nb) * 16;

  // register-resident B fragments: [gate][khalf][hi/lo]
  v8s B[4][2][2];
#pragma unroll
  for (int g = 0; g < 4; ++g)
#pragma unroll
    for (int kh = 0; kh < 2; ++kh)
#pragma unroll
      for (int p = 0; p < 2; ++p)
        B[g][kh][p] = pk[((((wv * 4 + g) * 2 + kh) * 2 + p) << 6) + lane];

  // per-lane input-projection constants (C-layout column n = g*64+16wv+jc)
  const int jc = lane & 15, qc = lane >> 4;  // C roles: unit col, seq quad
  float wi0[4], wi1[4], bs[4];
#pragma unroll
  for (int g = 0; g < 4; ++g) {
    int n = g * 64 + 16 * wv + jc;
    wi0[g] = Wih[n * 2 + 0];
    wi1[g] = Wih[n * 2 + 1];
    bs[g] = bih[n] + bhh[n];
  }

  // stage x (16 seqs x 50 t x 2 = 1600 contiguous floats) + zero h planes
  {
    const float4* xb = (const float4*)(xsrc + (size_t)s0 * 100);
    for (int i = tid; i < 400; i += 256) ((float4*)xst)[i] = xb[i];
    for (int i = tid; i < 1152; i += 256) hpl[i] = 0;
  }
  __syncthreads();

  const int ms = lane & 15, ks = lane >> 4;  // A-read roles: seq, k-quad
  const int parity = jc & 1;
  const int jp = 8 * wv + (jc >> 1);
  float cst[4] = {0.f, 0.f, 0.f, 0.f};
  float h[4];

  for (int t = 0; t < T_SEQ; ++t) {
    // A fragments from h planes (zero at t=0)
    v8s Ahi[2], Alo[2];
#pragma unroll
    for (int kh = 0; kh < 2; ++kh) {
      Ahi[kh] = *(const __shared__ v8s*)&hpl[ms * 36 + kh * 16 + ks * 4];
      Alo[kh] = *(const __shared__ v8s*)&hpl[576 + ms * 36 + kh * 16 + ks * 4];
    }
    __syncthreads();  // reads landed; safe to overwrite planes later

    // acc init: exact fp32 input projection + bias
    v4f a4[4];
#pragma unroll
    for (int r = 0; r < 4; ++r) {
      v2f xv = *(const __shared__ v2f*)&xst[(qc * 4 + r) * 100 + 2 * t];
#pragma unroll
      for (int g = 0; g < 4; ++g)
        a4[g][r] = fmaf(wi1[g], xv.y, fmaf(wi0[g], xv.x, bs[g]));
    }

    // h @ Whh^T via bf16x3 MFMA
#pragma unroll
    for (int g = 0; g < 4; ++g)
#pragma unroll
      for (int kh = 0; kh < 2; ++kh) {
        a4[g] = mfma16(Ahi[kh], B[g][kh][0], a4[g]);
        a4[g] = mfma16(Ahi[kh], B[g][kh][1], a4[g]);
        a4[g] = mfma16(Alo[kh], B[g][kh][0], a4[g]);
      }

    // pointwise LSTM update (4 cells/lane: seqs qc*4+r, unit 16wv+jc)
    unsigned words[4];
#pragma unroll
    for (int r = 0; r < 4; ++r) {
      float iv = a4[0][r], fv = a4[1][r], gv = a4[2][r], ov = a4[3][r];
      cst[r] = sigf(fv) * cst[r] + sigf(iv) * tanhf_fast(gv);
      h[r] = sigf(ov) * tanhf_fast(cst[r]);
      // split h -> bf16 hi/lo, pack word = hi16 | (lo16<<16)
      unsigned u = __float_as_uint(h[r]);
      unsigned t1 = u + 0x7fff + ((u >> 16) & 1);
      float hif = __uint_as_float(t1 & 0xffff0000u);
      float lo = h[r] - hif;
      unsigned ul = __float_as_uint(lo);
      ul += 0x7fff + ((ul >> 16) & 1);
      words[r] = (t1 >> 16) | (ul & 0xffff0000u);
    }

    // pair-exchange (unit j with j^1) and store to hi/lo planes
#pragma unroll
    for (int r = 0; r < 4; ++r) {
      unsigned pw = (unsigned)__builtin_amdgcn_ds_swizzle((int)words[r], 0x041F);
      unsigned pairw = parity ? ((pw >> 16) | (words[r] & 0xffff0000u))
                              : ((words[r] & 0xffffu) | (pw << 16));
      hpl[(parity ? 576 : 0) + (qc * 4 + r) * 36 + jp] = pairw;
    }
    __syncthreads();
  }

  // write final h (fp32)
#pragma unroll
  for (int r = 0; r < 4; ++r)
    outp[(size_t)(s0 + qc * 4 + r) * 64 + 16 * wv + jc] = h[r];
}

// Masked neighbour max-pool + concat -> h0 [B,128]
__global__ void hmax_kernel(const float* __restrict__ aemb, const float* __restrict__ nenc,
                            const int* __restrict__ cnts, float* __restrict__ h0) {
  const int idx = blockIdx.x * 256 + threadIdx.x;  // 2048*64
  const int b = idx >> 6, j = idx & 63;
  h0[(size_t)b * 128 + j] = aemb[(size_t)b * 64 + j];
  const int cnt = cnts[b];
  float m = -1e30f;
  for (int n = 0; n < cnt; ++n) m = fmaxf(m, nenc[((size_t)(b * NMAX + n)) * 64 + j]);
  h0[(size_t)b * 128 + 64 + j] = (cnt > 0) ? m : 0.f;
}

// ---------------------------------------------------------------------------
// Decoder (unchanged R3): 256 blocks x 4 waves, split-K, pk_fma.
// ---------------------------------------------------------------------------
__global__ __launch_bounds__(256, 4) void dec_kernel(
    const v4f* __restrict__ Wd, const v4f* __restrict__ bd4,
    const float* __restrict__ h0, const float* __restrict__ Wpos,
    const float* __restrict__ bpos, float* __restrict__ out) {
  __shared__ v4f pLo[4][8][64];
  __shared__ v4f pHi[4][8][64];
  __shared__ float hLds[8][128];
  const int lane = threadIdx.x & 63, wv = threadIdx.x >> 6;
  const int sBase = blockIdx.x * 8;
  const int k0 = wv * 32;
  const int sA = 2 * wv, sB = 2 * wv + 1;

  const v4f blo4 = bd4[lane], bhi4 = bd4[64 + lane];
  const v2f bloIf = __builtin_shufflevector(blo4, blo4, 0, 1);
  const v2f bloGo = __builtin_shufflevector(blo4, blo4, 2, 3);
  const v2f bhiIf = __builtin_shufflevector(bhi4, bhi4, 0, 1);
  const v2f bhiGo = __builtin_shufflevector(bhi4, bhi4, 2, 3);
  const float wp0l = Wpos[lane], wp0h = Wpos[64 + lane];
  const float wp1l = Wpos[128 + lane], wp1h = Wpos[192 + lane];
  const float bp0 = bpos[0], bp1 = bpos[1];

  float hLoA = h0[(size_t)(sBase + sA) * 128 + lane];
  float hHiA = h0[(size_t)(sBase + sA) * 128 + 64 + lane];
  float hLoB = h0[(size_t)(sBase + sB) * 128 + lane];
  float hHiB = h0[(size_t)(sBase + sB) * 128 + 64 + lane];
  float cLoA = 0.f, cHiA = 0.f, cLoB = 0.f, cHiB = 0.f;
  hLds[sA][lane] = hLoA; hLds[sA][64 + lane] = hHiA;
  hLds[sB][lane] = hLoB; hLds[sB][64 + lane] = hHiB;
  __syncthreads();

  const v2f z2 = {0.f, 0.f};

  for (int t = 0; t < PRED_STEPS; ++t) {
    float hreg[4];
#pragma unroll
    for (int si = 0; si < 4; ++si)
      hreg[si] = hLds[2 * si + (lane >> 5)][k0 + (lane & 31)];

    v2f aLoIf[8], aLoGo[8], aHiIf[8], aHiGo[8];
#pragma unroll
    for (int s = 0; s < 8; ++s) {
      aLoIf[s] = (wv == 0) ? bloIf : z2; aLoGo[s] = (wv == 0) ? bloGo : z2;
      aHiIf[s] = (wv == 0) ? bhiIf : z2; aHiGo[s] = (wv == 0) ? bhiGo : z2;
    }
#pragma unroll 2
    for (int kk = 0; kk < 32; ++kk) {
      const v4f wlo4 = Wd[((k0 + kk) << 7) + lane];
      const v4f whi4 = Wd[((k0 + kk) << 7) + 64 + lane];
      const v2f wloIf = __builtin_shufflevector(wlo4, wlo4, 0, 1);
      const v2f wloGo = __builtin_shufflevector(wlo4, wlo4, 2, 3);
      const v2f whiIf = __builtin_shufflevector(whi4, whi4, 0, 1);
      const v2f whiGo = __builtin_shufflevector(whi4, whi4, 2, 3);
#pragma unroll
      for (int s = 0; s < 8; ++s) {
        const uint64_t hb = bcast(hreg[s >> 1], ((s & 1) << 5) | kk);
        pk_fma_s(aLoIf[s], wloIf, hb); pk_fma_s(aLoGo[s], wloGo, hb);
        pk_fma_s(aHiIf[s], whiIf, hb); pk_fma_s(aHiGo[s], whiGo, hb);
      }
    }
#pragma unroll
    for (int s = 0; s < 8; ++s) {
      pLo[wv][s][lane] = __builtin_shufflevector(aLoIf[s], aLoGo[s], 0, 1, 2, 3);
      pHi[wv][s][lane] = __builtin_shufflevector(aHiIf[s], aHiGo[s], 0, 1, 2, 3);
    }
    __syncthreads();

    v4f gLoA = pLo[0][sA][lane], gHiA = pHi[0][sA][lane];
    v4f gLoB = pLo[0][sB][lane], gHiB = pHi[0][sB][lane];
#pragma unroll
    for (int w = 1; w < 4; ++w) {
      gLoA += pLo[w][sA][lane]; gHiA += pHi[w][sA][lane];
      gLoB += pLo[w][sB][lane]; gHiB += pHi[w][sB][lane];
    }
    cLoA = sigf(gLoA.y) * cLoA + sigf(gLoA.x) * tanhf_fast(gLoA.z);
    hLoA = sigf(gLoA.w) * tanhf_fast(cLoA);
    cHiA = sigf(gHiA.y) * cHiA + sigf(gHiA.x) * tanhf_fast(gHiA.z);
    hHiA = sigf(gHiA.w) * tanhf_fast(cHiA);
    cLoB = sigf(gLoB.y) * cLoB + sigf(gLoB.x) * tanhf_fast(gLoB.z);
    hLoB = sigf(gLoB.w) * tanhf_fast(cLoB);
    cHiB = sigf(gHiB.y) * cHiB + sigf(gHiB.x) * tanhf_fast(gHiB.z);
    hHiB = sigf(gHiB.w) * tanhf_fast(cHiB);

    hLds[sA][lane] = hLoA; hLds[sA][64 + lane] = hHiA;
    hLds[sB][lane] = hLoB; hLds[sB][64 + lane] = hHiB;

    float p0A = hLoA * wp0l + hHiA * wp0h;
    float p1A = hLoA * wp1l + hHiA * wp1h;
    float p0B = hLoB * wp0l + hHiB * wp0h;
    float p1B = hLoB * wp1l + hHiB * wp1h;
#pragma unroll
    for (int off = 32; off > 0; off >>= 1) {
      p0A += __shfl_xor(p0A, off, 64); p1A += __shfl_xor(p1A, off, 64);
      p0B += __shfl_xor(p0B, off, 64); p1B += __shfl_xor(p1B, off, 64);
    }
    if (lane == 0) {
      out[(size_t)(sBase + sA) * (PRED_STEPS * 2) + t * 2 + 0] = p0A + bp0;
      out[(size_t)(sBase + sA) * (PRED_STEPS * 2) + t * 2 + 1] = p1A + bp1;
      out[(size_t)(sBase + sB) * (PRED_STEPS * 2) + t * 2 + 0] = p0B + bp0;
      out[(size_t)(sBase + sB) * (PRED_STEPS * 2) + t * 2 + 1] = p1B + bp1;
    }
    __syncthreads();
  }
}

extern "C" void kernel_launch(void* const* d_in, const int* in_sizes, int n_in,
                              void* d_out, int out_size, void* d_ws, size_t ws_size,
                              hipStream_t stream) {
  (void)in_sizes; (void)n_in; (void)out_size; (void)ws_size;
  const float* xA    = (const float*)d_in[0];
  const float* xN    = (const float*)d_in[1];
  const int*   cnts  = (const int*)d_in[2];
  const float* Wih_a = (const float*)d_in[3];
  const float* Whh_a = (const float*)d_in[4];
  const float* bih_a = (const float*)d_in[5];
  const float* bhh_a = (const float*)d_in[6];
  const float* Wih_n = (const float*)d_in[7];
  const float* Whh_n = (const float*)d_in[8];
  const float* bih_n = (const float*)d_in[9];
  const float* bhh_n = (const float*)d_in[10];
  const float* Wih_d = (const float*)d_in[11];
  const float* Whh_d = (const float*)d_in[12];
  const float* bih_d = (const float*)d_in[13];
  const float* bhh_d = (const float*)d_in[14];
  const float* Wpos  = (const float*)d_in[15];
  const float* bpos  = (const float*)d_in[16];
  float* out = (float*)d_out;
  float* wsf = (float*)d_ws;

  prep_encpack<<<32, 256, 0, stream>>>(Whh_a, Whh_n,
                                       (uint4*)(wsf + OFF_PACKA),
                                       (uint4*)(wsf + OFF_PACKN));
  prep_dec_kernel<<<64, 256, 0, stream>>>(Wih_d, Whh_d, bih_d, bhh_d, wsf);
  enc_mfma_kernel<<<2176, 256, 0, stream>>>(
      xA, xN,
      (const v8s*)(wsf + OFF_PACKA), (const v8s*)(wsf + OFF_PACKN),
      Wih_a, bih_a, bhh_a, Wih_n, bih_n, bhh_n,
      wsf + OFF_AEMB, wsf + OFF_NENC);
  hmax_kernel<<<512, 256, 0, stream>>>(wsf + OFF_AEMB, wsf + OFF_NENC, cnts, wsf + OFF_H0);
  dec_kernel<<<256, 256, 0, stream>>>((const v4f*)(wsf + OFF_WD),
                                      (const v4f*)(wsf + OFF_WD + 65536),
                                      wsf + OFF_H0, Wpos, bpos, out);
}

// Round 5
// 462.286 us; speedup vs baseline: 9.0649x; 1.1423x over previous
//
#include <hip/hip_runtime.h>
#include <stdint.h>

// ---------------------------------------------------------------------------
// Social LSTM model, bf16x3 MFMA everywhere.
//   enc:  LSTM(2->64), T=50, 2176 blocks x 4 waves, 16 seqs/block.
//         Whh register-resident B-frags (hi/lo). h LDS planes, b16 writes.
//   pool: masked max over valid neighbours, concat -> h0 [2048,128]
//   dec:  LSTMCell(128->128), 30 steps. 128 blocks x 4 waves, 16 seqs/block.
//         Wave owns 32 units x 4 gates; B streamed from L2 per step.
// Pointwise: shared-rcp sigmoid/tanh algebra (7 transcendentals/cell).
// ---------------------------------------------------------------------------

#define T_SEQ 50
#define PRED_STEPS 30
#define NMAX 16

typedef float v2f __attribute__((ext_vector_type(2)));
typedef float v4f __attribute__((ext_vector_type(4)));
typedef short v8s __attribute__((ext_vector_type(8)));

// ws layout (float offsets)
static constexpr size_t OFF_AEMB  = 0;          // 2048*64
static constexpr size_t OFF_NENC  = 131072;     // 32768*64
static constexpr size_t OFF_H0    = 2228224;    // 2048*128
static constexpr size_t OFF_PACKA = 2490368;    // 64 KB bf16 B-frags (agent)
static constexpr size_t OFF_PACKN = 2507520;    // 64 KB bf16 B-frags (neigh)
static constexpr size_t OFF_WDP   = 2524672;    // 256 KB dec bf16 B-frags
static constexpr size_t OFF_WDB   = 2590208;    // 512 fused dec bias

__device__ __forceinline__ float frcp(float x) { return __builtin_amdgcn_rcpf(x); }
__device__ __forceinline__ unsigned bf16rne(float f) {
  unsigned u = __float_as_uint(f);
  u += 0x7fff + ((u >> 16) & 1);
  return u >> 16;
}
__device__ __forceinline__ float bf16tof(unsigned h) { return __uint_as_float(h << 16); }
__device__ __forceinline__ v4f mfma16(v8s a, v8s b, v4f c) {
  return __builtin_amdgcn_mfma_f32_16x16x32_bf16(a, b, c, 0, 0, 0);
}

// Shared-rcp LSTM cell update: given gates i,f,g,o and c, produce (c',h).
// sig(f) = t1*r ; sig(i)*tanh(g) = (1-eg)*(1+ef)*r ; r = rcp((1+ef)*t1).
// ec clamped (c can grow over t); other exps bounded by |gate|<~20 << 88.
__device__ __forceinline__ float cell_update(float iv, float fv, float gv,
                                             float ov, float& cref) {
  float ef = __expf(-fv);
  float ei = __expf(-iv);
  float eg = __expf(-2.f * gv);
  float t1 = (1.f + ei) * (1.f + eg);
  float rD = frcp((1.f + ef) * t1);
  float sf = t1 * rD;
  float u  = (1.f - eg) * ((1.f + ef) * rD);
  float cn = fmaf(sf, cref, u);
  cref = cn;
  float eo = __expf(-ov);
  float ec = __expf(fminf(-2.f * cn, 41.5f));
  return (1.f - ec) * frcp((1.f + eo) * (1.f + ec));
}

// ---------------------------------------------------------------------------
// Prep: encoder Whh as MFMA B-fragments, bf16 hi/lo split (RNE).
// chunk c = ((w*4+g)*2+kh)*2+p ; lane l: n=l&15 -> unit 16w+n, k=(l>>4)*8+e.
// ---------------------------------------------------------------------------
__global__ void prep_encpack(const float* __restrict__ Whh_a, const float* __restrict__ Whh_n,
                             uint4* __restrict__ packA, uint4* __restrict__ packN) {
  const int which = blockIdx.x >> 4;
  const int idx = (blockIdx.x & 15) * 256 + threadIdx.x;  // 0..4095
  const float* Whh = which ? Whh_n : Whh_a;
  uint4* dst = which ? packN : packA;
  const int lane = idx & 63, c = idx >> 6;
  const int p = c & 1, kh = (c >> 1) & 1, g = (c >> 2) & 3, w = (c >> 4) & 3;
  const int row = g * 64 + 16 * w + (lane & 15);
  const int kb = kh * 32 + (lane >> 4) * 8;
  unsigned us[8];
#pragma unroll
  for (int e = 0; e < 8; ++e) {
    float W = Whh[row * 64 + kb + e];
    unsigned hi = bf16rne(W);
    us[e] = p ? bf16rne(W - bf16tof(hi)) : hi;
  }
  uint4 o;
  o.x = us[0] | (us[1] << 16);
  o.y = us[2] | (us[3] << 16);
  o.z = us[4] | (us[5] << 16);
  o.w = us[6] | (us[7] << 16);
  dst[c * 64 + lane] = o;
}

// ---------------------------------------------------------------------------
// Prep: decoder fused W = Wih_d + Whh_d as B-frags (bf16 hi/lo).
// chunk c: bits [7:6]=wv [5:4]=g [3]=uh [2:1]=kh [0]=p.
// lane: unit j = 32wv+16uh+(l&15), k = kh*32+(l>>4)*8+e, row = g*128+j.
// ---------------------------------------------------------------------------
__global__ void prep_decpack(const float* __restrict__ Wih, const float* __restrict__ Whh,
                             const float* __restrict__ bih, const float* __restrict__ bhh,
                             uint4* __restrict__ dst, float* __restrict__ bd) {
  const int idx = blockIdx.x * 256 + threadIdx.x;  // 0..16383
  const int lane = idx & 63, c = idx >> 6;
  const int p = c & 1, kh = (c >> 1) & 3, uh = (c >> 3) & 1, g = (c >> 4) & 3, wv = (c >> 6) & 3;
  const int j = 32 * wv + 16 * uh + (lane & 15);
  const int row = g * 128 + j;
  const int kb = kh * 32 + (lane >> 4) * 8;
  unsigned us[8];
#pragma unroll
  for (int e = 0; e < 8; ++e) {
    float W = Wih[row * 128 + kb + e] + Whh[row * 128 + kb + e];
    unsigned hi = bf16rne(W);
    us[e] = p ? bf16rne(W - bf16tof(hi)) : hi;
  }
  uint4 o;
  o.x = us[0] | (us[1] << 16);
  o.y = us[2] | (us[3] << 16);
  o.z = us[4] | (us[5] << 16);
  o.w = us[6] | (us[7] << 16);
  dst[c * 64 + lane] = o;
  if (blockIdx.x < 2) {
    int i = blockIdx.x * 256 + threadIdx.x;  // 0..511
    bd[i] = bih[i] + bhh[i];
  }
}

// ---------------------------------------------------------------------------
// Encoder. Blocks [0,2048) neighbour, [2048,2176) agent; 256 thr = 4 waves.
// h planes: halfwords, row stride 72 (36 words, 16B-aligned b128 reads),
// hi at [0,1152), lo at [1152,2304).
// ---------------------------------------------------------------------------
__global__ __launch_bounds__(256, 3) void enc_mfma_kernel(
    const float* __restrict__ xA, const float* __restrict__ xN,
    const v8s* __restrict__ packA, const v8s* __restrict__ packN,
    const float* __restrict__ Wih_a, const float* __restrict__ bih_a, const float* __restrict__ bhh_a,
    const float* __restrict__ Wih_n, const float* __restrict__ bih_n, const float* __restrict__ bhh_n,
    float* __restrict__ outA, float* __restrict__ outN) {
  __shared__ unsigned short hph[2304];
  __shared__ float xst[1600];
  const int tid = threadIdx.x, lane = tid & 63, wv = tid >> 6;
  const int nb = blockIdx.x;
  const bool isA = nb >= 2048;
  const float* xsrc = isA ? xA : xN;
  const v8s* pk = isA ? packA : packN;
  const float* Wih = isA ? Wih_a : Wih_n;
  const float* bih = isA ? bih_a : bih_n;
  const float* bhh = isA ? bhh_a : bhh_n;
  float* outp = isA ? outA : outN;
  const int s0 = (isA ? nb - 2048 : nb) * 16;

  // register-resident B fragments: [gate][khalf][hi/lo]
  v8s B[4][2][2];
#pragma unroll
  for (int g = 0; g < 4; ++g)
#pragma unroll
    for (int kh = 0; kh < 2; ++kh)
#pragma unroll
      for (int p = 0; p < 2; ++p)
        B[g][kh][p] = pk[((((wv * 4 + g) * 2 + kh) * 2 + p) << 6) + lane];

  const int jc = lane & 15, qc = lane >> 4;  // C roles: unit col, seq quad
  float wi0[4], wi1[4], bs[4];
#pragma unroll
  for (int g = 0; g < 4; ++g) {
    int n = g * 64 + 16 * wv + jc;
    wi0[g] = Wih[n * 2 + 0];
    wi1[g] = Wih[n * 2 + 1];
    bs[g] = bih[n] + bhh[n];
  }

  // stage x (1600 floats) + zero h planes (1152 words)
  {
    const float4* xb = (const float4*)(xsrc + (size_t)s0 * 100);
    for (int i = tid; i < 400; i += 256) ((float4*)xst)[i] = xb[i];
    for (int i = tid; i < 1152; i += 256) ((unsigned*)hph)[i] = 0;
  }
  __syncthreads();

  const int ms = lane & 15, ks = lane >> 4;  // A roles: seq row, k-quad
  float cst[4] = {0.f, 0.f, 0.f, 0.f};
  float h[4];

  for (int t = 0; t < T_SEQ; ++t) {
    v8s Ahi[2], Alo[2];
#pragma unroll
    for (int kh = 0; kh < 2; ++kh) {
      Ahi[kh] = *(const __shared__ v8s*)&hph[ms * 72 + kh * 32 + ks * 8];
      Alo[kh] = *(const __shared__ v8s*)&hph[1152 + ms * 72 + kh * 32 + ks * 8];
    }
    __syncthreads();  // A-reads landed before plane overwrite below

    // acc init: exact fp32 input projection + bias
    v4f a4[4];
#pragma unroll
    for (int r = 0; r < 4; ++r) {
      v2f xv = *(const __shared__ v2f*)&xst[(qc * 4 + r) * 100 + 2 * t];
#pragma unroll
      for (int g = 0; g < 4; ++g)
        a4[g][r] = fmaf(wi1[g], xv.y, fmaf(wi0[g], xv.x, bs[g]));
    }

    // h @ Whh^T via bf16x3 MFMA
#pragma unroll
    for (int g = 0; g < 4; ++g)
#pragma unroll
      for (int kh = 0; kh < 2; ++kh) {
        a4[g] = mfma16(Ahi[kh], B[g][kh][0], a4[g]);
        a4[g] = mfma16(Ahi[kh], B[g][kh][1], a4[g]);
        a4[g] = mfma16(Alo[kh], B[g][kh][0], a4[g]);
      }

    // pointwise + truncation-split b16 stores
#pragma unroll
    for (int r = 0; r < 4; ++r) {
      h[r] = cell_update(a4[0][r], a4[1][r], a4[2][r], a4[3][r], cst[r]);
      unsigned uu = __float_as_uint(h[r]);
      float hif = __uint_as_float(uu & 0xffff0000u);
      float lof = h[r] - hif;
      int ha = (qc * 4 + r) * 72 + 16 * wv + jc;
      hph[ha] = (unsigned short)(uu >> 16);
      hph[1152 + ha] = (unsigned short)(__float_as_uint(lof) >> 16);
    }
    __syncthreads();
  }

#pragma unroll
  for (int r = 0; r < 4; ++r)
    outp[(size_t)(s0 + qc * 4 + r) * 64 + 16 * wv + jc] = h[r];
}

// Masked neighbour max-pool + concat -> h0 [B,128]
__global__ void hmax_kernel(const float* __restrict__ aemb, const float* __restrict__ nenc,
                            const int* __restrict__ cnts, float* __restrict__ h0) {
  const int idx = blockIdx.x * 256 + threadIdx.x;  // 2048*64
  const int b = idx >> 6, j = idx & 63;
  h0[(size_t)b * 128 + j] = aemb[(size_t)b * 64 + j];
  const int cnt = cnts[b];
  float m = -1e30f;
  for (int n = 0; n < cnt; ++n) m = fmaxf(m, nenc[((size_t)(b * NMAX + n)) * 64 + j]);
  h0[(size_t)b * 128 + 64 + j] = (cnt > 0) ? m : 0.f;
}

// ---------------------------------------------------------------------------
// Decoder MFMA. 128 blocks x 256 thr (4 waves), 16 seqs/block.
// Wave wv owns units [32wv,32wv+32) x 4 gates = 8 col-tiles; K=128 full.
// B streamed from L2 each step. h planes: halfwords, row stride 136,
// hi [0,2176), lo [2176,4352). Pred via register partials + shuffle.
// ---------------------------------------------------------------------------
__global__ __launch_bounds__(256, 2) void dec_mfma_kernel(
    const v8s* __restrict__ pkd, const float* __restrict__ bd,
    const float* __restrict__ h0, const float* __restrict__ Wpos,
    const float* __restrict__ bpos, float* __restrict__ out) {
  __shared__ unsigned short hph[4352];
  __shared__ float part[4][16][2];
  const int tid = threadIdx.x, lane = tid & 63, wv = tid >> 6;
  const int jc = lane & 15, qc = lane >> 4;
  const int s0 = blockIdx.x * 16;

  float bs[2][4], wp[2][2];
#pragma unroll
  for (int uh = 0; uh < 2; ++uh) {
    int ju = 32 * wv + 16 * uh + jc;
#pragma unroll
    for (int g = 0; g < 4; ++g) bs[uh][g] = bd[g * 128 + ju];
    wp[0][uh] = Wpos[ju];
    wp[1][uh] = Wpos[128 + ju];
  }
  const float bp = bpos[tid & 1];

  // stage h0 -> planes (truncation split)
  for (int i = tid; i < 2048; i += 256) {
    int row = i >> 7, unit = i & 127;
    float v = h0[(size_t)(s0 + row) * 128 + unit];
    unsigned u = __float_as_uint(v);
    float hif = __uint_as_float(u & 0xffff0000u);
    float lof = v - hif;
    hph[row * 136 + unit] = (unsigned short)(u >> 16);
    hph[2176 + row * 136 + unit] = (unsigned short)(__float_as_uint(lof) >> 16);
  }
  float cst[8];
#pragma unroll
  for (int i = 0; i < 8; ++i) cst[i] = 0.f;
  __syncthreads();

  const int ms = jc, ks = qc;
  for (int t = 0; t < PRED_STEPS; ++t) {
    v8s Ahi[4], Alo[4];
#pragma unroll
    for (int kh = 0; kh < 4; ++kh) {
      Ahi[kh] = *(const __shared__ v8s*)&hph[ms * 136 + kh * 32 + ks * 8];
      Alo[kh] = *(const __shared__ v8s*)&hph[2176 + ms * 136 + kh * 32 + ks * 8];
    }
    __syncthreads();  // barrier1: A-reads done before plane rewrite

    float hC[8];
#pragma unroll 1
    for (int uh = 0; uh < 2; ++uh) {
      v4f acc[4];
#pragma unroll
      for (int g = 0; g < 4; ++g)
        acc[g] = (v4f){bs[uh][g], bs[uh][g], bs[uh][g], bs[uh][g]};
#pragma unroll
      for (int g = 0; g < 4; ++g) {
        const v8s* cb = pkd + (((wv * 64 + g * 16 + uh * 8) << 6) + lane);
#pragma unroll
        for (int kh = 0; kh < 4; ++kh) {
          v8s Bhi = cb[(kh * 2 + 0) << 6];
          v8s Blo = cb[(kh * 2 + 1) << 6];
          acc[g] = mfma16(Ahi[kh], Bhi, acc[g]);
          acc[g] = mfma16(Ahi[kh], Blo, acc[g]);
          acc[g] = mfma16(Alo[kh], Bhi, acc[g]);
        }
      }
#pragma unroll
      for (int r = 0; r < 4; ++r) {
        float hv = cell_update(acc[0][r], acc[1][r], acc[2][r], acc[3][r],
                               cst[uh * 4 + r]);
        hC[uh * 4 + r] = hv;
        unsigned uu = __float_as_uint(hv);
        float hif = __uint_as_float(uu & 0xffff0000u);
        float lof = hv - hif;
        int ha = (qc * 4 + r) * 136 + 32 * wv + 16 * uh + jc;
        hph[ha] = (unsigned short)(uu >> 16);
        hph[2176 + ha] = (unsigned short)(__float_as_uint(lof) >> 16);
      }
    }

    // pred partials: each lane covers its 2 units for its 4 rows
    float pp0[4], pp1[4];
#pragma unroll
    for (int r = 0; r < 4; ++r) {
      pp0[r] = hC[r] * wp[0][0] + hC[4 + r] * wp[0][1];
      pp1[r] = hC[r] * wp[1][0] + hC[4 + r] * wp[1][1];
#pragma unroll
      for (int off = 1; off < 16; off <<= 1) {
        pp0[r] += __shfl_xor(pp0[r], off, 64);
        pp1[r] += __shfl_xor(pp1[r], off, 64);
      }
    }
    if (jc == 0) {
#pragma unroll
      for (int r = 0; r < 4; ++r) {
        part[wv][qc * 4 + r][0] = pp0[r];
        part[wv][qc * 4 + r][1] = pp1[r];
      }
    }
    __syncthreads();  // barrier2: h planes + partials visible
    if (tid < 32) {
      int row = tid >> 1, coord = tid & 1;
      float p = part[0][row][coord] + part[1][row][coord] +
                part[2][row][coord] + part[3][row][coord] + bp;
      out[(size_t)(s0 + row) * (PRED_STEPS * 2) + t * 2 + coord] = p;
    }
  }
}

extern "C" void kernel_launch(void* const* d_in, const int* in_sizes, int n_in,
                              void* d_out, int out_size, void* d_ws, size_t ws_size,
                              hipStream_t stream) {
  (void)in_sizes; (void)n_in; (void)out_size; (void)ws_size;
  const float* xA    = (const float*)d_in[0];
  const float* xN    = (const float*)d_in[1];
  const int*   cnts  = (const int*)d_in[2];
  const float* Wih_a = (const float*)d_in[3];
  const float* Whh_a = (const float*)d_in[4];
  const float* bih_a = (const float*)d_in[5];
  const float* bhh_a = (const float*)d_in[6];
  const float* Wih_n = (const float*)d_in[7];
  const float* Whh_n = (const float*)d_in[8];
  const float* bih_n = (const float*)d_in[9];
  const float* bhh_n = (const float*)d_in[10];
  const float* Wih_d = (const float*)d_in[11];
  const float* Whh_d = (const float*)d_in[12];
  const float* bih_d = (const float*)d_in[13];
  const float* bhh_d = (const float*)d_in[14];
  const float* Wpos  = (const float*)d_in[15];
  const float* bpos  = (const float*)d_in[16];
  float* out = (float*)d_out;
  float* wsf = (float*)d_ws;

  prep_encpack<<<32, 256, 0, stream>>>(Whh_a, Whh_n,
                                       (uint4*)(wsf + OFF_PACKA),
                                       (uint4*)(wsf + OFF_PACKN));
  prep_decpack<<<64, 256, 0, stream>>>(Wih_d, Whh_d, bih_d, bhh_d,
                                       (uint4*)(wsf + OFF_WDP), wsf + OFF_WDB);
  enc_mfma_kernel<<<2176, 256, 0, stream>>>(
      xA, xN,
      (const v8s*)(wsf + OFF_PACKA), (const v8s*)(wsf + OFF_PACKN),
      Wih_a, bih_a, bhh_a, Wih_n, bih_n, bhh_n,
      wsf + OFF_AEMB, wsf + OFF_NENC);
  hmax_kernel<<<512, 256, 0, stream>>>(wsf + OFF_AEMB, wsf + OFF_NENC, cnts, wsf + OFF_H0);
  dec_mfma_kernel<<<128, 256, 0, stream>>>((const v8s*)(wsf + OFF_WDP),
                                           wsf + OFF_WDB, wsf + OFF_H0,
                                           Wpos, bpos, out);
}